// Round 2
// baseline (8403.661 us; speedup 1.0000x reference)
//
#include <hip/hip_runtime.h>

#define N_NODES 50000
#define N_EDGE  150000
#define N_GRAPH 200
#define DIM     320
#define EDI     15
#define EH      32
#define NBLK    3
#define NTYP    9

typedef unsigned short u16;
typedef unsigned int   u32;
typedef __bf16 bf16x8 __attribute__((ext_vector_type(8)));
typedef float  f32x4  __attribute__((ext_vector_type(4)));

__device__ __forceinline__ float b2f(u16 s) {
    u32 u = ((u32)s) << 16;
    return __builtin_bit_cast(float, u);
}
__device__ __forceinline__ u16 f2b(float f) {
    u32 u = __builtin_bit_cast(u32, f);
    u = (u + 0x7fffu + ((u >> 16) & 1u)) >> 16;
    return (u16)u;
}

// ---------------------------------------------------------------------------
// Generic bf16 MFMA GEMM: C[M x out_cols] = A[M x K] @ Bst + bias
// A: bf16 row-major, row stride lda (elements). K = KQ*8.
// Bst: staged weights, layout [KQ][NP][8] bf16 (element (k,col) at
//      ((k>>3)*NP + col)*8 + (k&7)).
// mode: 0 = store bf16 to Cb ; 1 = store f32 to Cf ; 2 = Cf += (accumulate)
// Tile: 128x128, 4 waves of 64x64, BK=32 per iteration.
// ---------------------------------------------------------------------------
__global__ __launch_bounds__(256) void gemm_kernel(
    const u16* __restrict__ A, int lda,
    const u16* __restrict__ Bst, const float* __restrict__ bias,
    u16* __restrict__ Cb, float* __restrict__ Cf,
    int ldc, int out_cols, int M, int NP, int KQ, int mode)
{
    __shared__ u16 As[128 * 40];     // stride 40 (pad 8)
    __shared__ u16 Bs[4 * 128 * 8];  // [quad][col][8]
    const int tid = threadIdx.x;
    const int m0 = blockIdx.x * 128, n0 = blockIdx.y * 128;

    f32x4 acc[4][4] = {};
    const int nIter = KQ >> 2;

    for (int it = 0; it < nIter; ++it) {
        const int kq0 = it * 4;
#pragma unroll
        for (int c = 0; c < 2; ++c) {
            int i = tid + c * 256;
            int r = i >> 2, kc = i & 3;
            int gr = m0 + r; if (gr >= M) gr = M - 1;
            const uint4* src = (const uint4*)(A + (size_t)gr * lda + (kq0 + kc) * 8);
            *(uint4*)(&As[r * 40 + kc * 8]) = *src;
        }
#pragma unroll
        for (int c = 0; c < 2; ++c) {
            int i = tid + c * 256;
            int q = i >> 7, j = i & 127;
            const uint4* src = (const uint4*)(Bst + (((size_t)(kq0 + q) * NP + n0 + j) << 3));
            *(uint4*)(&Bs[i * 8]) = *src;
        }
        __syncthreads();

        const int wave = tid >> 6, lane = tid & 63;
        const int wm = (wave & 1) << 6, wn = (wave >> 1) << 6;
        const int lm = lane & 15, quad = lane >> 4;
        bf16x8 af[4], bfr[4];
#pragma unroll
        for (int mi = 0; mi < 4; ++mi)
            af[mi] = __builtin_bit_cast(bf16x8, *(const uint4*)(&As[(wm + mi * 16 + lm) * 40 + quad * 8]));
#pragma unroll
        for (int ni = 0; ni < 4; ++ni)
            bfr[ni] = __builtin_bit_cast(bf16x8, *(const uint4*)(&Bs[(quad * 128 + wn + ni * 16 + lm) * 8]));
#pragma unroll
        for (int mi = 0; mi < 4; ++mi)
#pragma unroll
            for (int ni = 0; ni < 4; ++ni)
                acc[mi][ni] = __builtin_amdgcn_mfma_f32_16x16x32_bf16(af[mi], bfr[ni], acc[mi][ni], 0, 0, 0);
        __syncthreads();
    }

    // epilogue: C/D layout col=lane&15, row=quad*4+reg
    const int wave = tid >> 6, lane = tid & 63;
    const int wm = (wave & 1) << 6, wn = (wave >> 1) << 6;
    const int lm = lane & 15, quad = lane >> 4;
#pragma unroll
    for (int mi = 0; mi < 4; ++mi) {
        int row = m0 + wm + mi * 16 + quad * 4;
#pragma unroll
        for (int ni = 0; ni < 4; ++ni) {
            int col = n0 + wn + ni * 16 + lm;
            float bv = bias ? bias[col] : 0.f;
#pragma unroll
            for (int r = 0; r < 4; ++r) {
                int rr = row + r;
                if (rr < M && col < out_cols) {
                    float v = acc[mi][ni][r] + bv;
                    size_t off = (size_t)rr * ldc + col;
                    if (mode == 0)      Cb[off] = f2b(v);
                    else if (mode == 1) Cf[off] = v;
                    else                Cf[off] += v;
                }
            }
        }
    }
}

// ---------------------------------------------------------------------------
// prep kernels
// ---------------------------------------------------------------------------
__global__ void k_init_head(int* __restrict__ head) {
    int i = blockIdx.x * 256 + threadIdx.x;
    if (i < NTYP * N_NODES) head[i] = -1;
}

__global__ void k_convert_x(const float* __restrict__ x, u16* __restrict__ hb) {
    size_t i = (size_t)blockIdx.x * 256 + threadIdx.x;
    if (i >= (size_t)N_NODES * DIM) return;
    hb[i] = f2b(x[i]);
}

// Bst_qkv: [27][40][1024][8]: cols 0-319 Wq | 320-639 Wk | 640-959 Wv |
// 960-991 Wq@We^T | 992 Wq@be | 993-1023 zero
__global__ void k_prep_qkvW(const float* __restrict__ Wq, const float* __restrict__ Wk,
                            const float* __restrict__ Wv, const float* __restrict__ We,
                            const float* __restrict__ be, u16* __restrict__ Bst) {
    size_t i = (size_t)blockIdx.x * 256 + threadIdx.x;
    if (i >= (size_t)27 * 320 * 1024) return;
    int col = (int)(i & 1023);
    int k   = (int)((i >> 10) % 320);
    int bt  = (int)(i / (320 * 1024));
    float v;
    if (col < 320)       v = Wq[((size_t)bt * 320 + k) * 320 + col];
    else if (col < 640)  v = Wk[((size_t)bt * 320 + k) * 320 + col - 320];
    else if (col < 960)  v = Wv[((size_t)bt * 320 + k) * 320 + col - 640];
    else if (col < 992) {
        const float* wq = Wq + ((size_t)bt * 320 + k) * 320;
        const float* we = We + ((size_t)bt * 32 + (col - 960)) * 320;
        float s = 0.f;
        for (int d = 0; d < 320; ++d) s += wq[d] * we[d];
        v = s;
    } else if (col == 992) {
        const float* wq = Wq + ((size_t)bt * 320 + k) * 320;
        const float* bv = be + (size_t)bt * 320;
        float s = 0.f;
        for (int d = 0; d < 320; ++d) s += wq[d] * bv[d];
        v = s;
    } else v = 0.f;
    Bst[(((size_t)bt * 40 + (k >> 3)) * 1024 + col) * 8 + (k & 7)] = f2b(v);
}

__global__ void k_prep_qkvB(const float* __restrict__ bq, const float* __restrict__ bk,
                            const float* __restrict__ bv, const float* __restrict__ We,
                            const float* __restrict__ be, float* __restrict__ bias) {
    int i = blockIdx.x * 256 + threadIdx.x;
    if (i >= 27 * 1024) return;
    int col = i & 1023, bt = i >> 10;
    float v;
    if (col < 320)       v = bq[bt * 320 + col];
    else if (col < 640)  v = bk[bt * 320 + col - 320];
    else if (col < 960)  v = bv[bt * 320 + col - 640];
    else if (col < 992) {
        const float* b = bq + bt * 320;
        const float* we = We + ((size_t)bt * 32 + (col - 960)) * 320;
        float s = 0.f;
        for (int d = 0; d < 320; ++d) s += b[d] * we[d];
        v = s;
    } else if (col == 992) {
        const float* b = bq + bt * 320;
        const float* bev = be + bt * 320;
        float s = 0.f;
        for (int d = 0; d < 320; ++d) s += b[d] * bev[d];
        v = s;
    } else v = 0.f;
    bias[i] = v;
}

// skip weights: sum over 9 types per block -> [3][40][384][8]
__global__ void k_prep_skipW(const float* __restrict__ Ws, u16* __restrict__ Bst) {
    int i = blockIdx.x * 256 + threadIdx.x;
    if (i >= 3 * 320 * 384) return;
    int col = i % 384, k = (i / 384) % 320, b = i / (384 * 320);
    float v = 0.f;
    if (col < 320)
        for (int t = 0; t < 9; ++t)
            v += Ws[((size_t)(b * 9 + t) * 320 + k) * 320 + col];
    Bst[(((size_t)b * 40 + (k >> 3)) * 384 + col) * 8 + (k & 7)] = f2b(v);
}
__global__ void k_prep_skipB(const float* __restrict__ bs, float* __restrict__ bias) {
    int i = blockIdx.x * 256 + threadIdx.x;
    if (i >= 3 * 384) return;
    int col = i % 384, b = i / 384;
    float v = 0.f;
    if (col < 320)
        for (int t = 0; t < 9; ++t) v += bs[(b * 9 + t) * 320 + col];
    bias[i] = v;
}

// We_ext for s-GEMM: K=64 -> [27][8][384][8]; row k<32 = We, k==32 = be, else 0
__global__ void k_prep_sWeW(const float* __restrict__ We, const float* __restrict__ be,
                            u16* __restrict__ Bst) {
    int i = blockIdx.x * 256 + threadIdx.x;
    if (i >= 27 * 64 * 384) return;
    int col = i % 384, k = (i / 384) % 64, bt = i / (384 * 64);
    float v = 0.f;
    if (col < 320) {
        if (k < 32)       v = We[((size_t)bt * 32 + k) * 320 + col];
        else if (k == 32) v = be[(size_t)bt * 320 + col];
    }
    Bst[(((size_t)bt * 8 + (k >> 3)) * 384 + col) * 8 + (k & 7)] = f2b(v);
}

// W1a|W1b staged for A-nodes GEMM: [40][128][8]
__global__ void k_prep_w1W(const float* __restrict__ W1, u16* __restrict__ Bst) {
    int i = blockIdx.x * 256 + threadIdx.x;
    if (i >= 320 * 128) return;
    int col = i & 127, k = i >> 7;
    float v = 0.f;
    if (col < 32)      v = W1[(size_t)k * 32 + col];
    else if (col < 64) v = W1[(size_t)(320 + k) * 32 + (col - 32)];
    Bst[((size_t)(k >> 3) * 128 + col) * 8 + (k & 7)] = f2b(v);
}

// per-dst linked lists
__global__ void k_build_lists(const int* __restrict__ eidx, int* __restrict__ head,
                              int* __restrict__ nxt) {
    size_t i = (size_t)blockIdx.x * 256 + threadIdx.x;
    if (i >= (size_t)NTYP * N_EDGE) return;
    int t = (int)(i / N_EDGE), e = (int)(i % N_EDGE);
    int dst = eidx[(size_t)(t * 2 + 1) * N_EDGE + e];
    nxt[i] = atomicExch(&head[t * N_NODES + dst], e);
}

// ---------------------------------------------------------------------------
// Edge MLP for one type t: out[e] = lrelu(A1[src]+A2[dst]+ea@W1c+b1)@W2 + b2
// ---------------------------------------------------------------------------
__global__ __launch_bounds__(256) void k_edge_mlp(
    const u16* __restrict__ Anodes, const int* __restrict__ eidx,
    const float* __restrict__ eattr, const float* __restrict__ W1,
    const float* __restrict__ b1, const float* __restrict__ W2,
    const float* __restrict__ b2, u16* __restrict__ outEa, int t)
{
    __shared__ float w1c[EDI][EH];
    __shared__ float w2s[EH][EH];
    __shared__ float b1s[EH], b2s[EH];
    int tid = threadIdx.x;
    for (int i = tid; i < EDI * EH; i += 256) w1c[i / EH][i % EH] = W1[(640 + i / EH) * EH + (i % EH)];
    for (int i = tid; i < EH * EH; i += 256) w2s[i / EH][i % EH] = W2[i];
    if (tid < EH) { b1s[tid] = b1[tid]; b2s[tid] = b2[tid]; }
    __syncthreads();

    int e = blockIdx.x * 256 + tid;
    if (e >= N_EDGE) return;
    int src = eidx[(size_t)(t * 2) * N_EDGE + e];
    int dst = eidx[(size_t)(t * 2 + 1) * N_EDGE + e];
    const float* eat = eattr + ((size_t)t * N_EDGE + e) * EDI;
    const u16* a1 = Anodes + (size_t)src * 64;
    const u16* a2 = Anodes + (size_t)dst * 64 + 32;

    float h1[EH];
#pragma unroll
    for (int j = 0; j < EH; ++j) h1[j] = b2f(a1[j]) + b2f(a2[j]) + b1s[j];
    for (int i = 0; i < EDI; ++i) {
        float v = eat[i];
#pragma unroll
        for (int j = 0; j < EH; ++j) h1[j] += v * w1c[i][j];
    }
#pragma unroll
    for (int j = 0; j < EH; ++j) h1[j] = h1[j] > 0.f ? h1[j] : 0.01f * h1[j];

    u16* orow = outEa + (size_t)e * EH;
    for (int j = 0; j < EH; ++j) {
        float o = b2s[j];
#pragma unroll
        for (int i = 0; i < EH; ++i) o += h1[i] * w2s[i][j];
        orow[j] = f2b(o);
    }
}

// ---------------------------------------------------------------------------
// Attention: one wave per dst node, online softmax over its linked edge list.
// ---------------------------------------------------------------------------
__global__ __launch_bounds__(256) void k_attn(
    const u16* __restrict__ qkv, const int* __restrict__ head,
    const int* __restrict__ nxt, const int* __restrict__ srcArr,
    const u16* __restrict__ ea, float* __restrict__ acc, u16* __restrict__ sbuf)
{
    int wave = threadIdx.x >> 6, lane = threadIdx.x & 63;
    int n = blockIdx.x * 4 + wave;
    if (n >= N_NODES) return;
    const u16* qrow = qkv + (size_t)n * 1024;
    float q[5];
#pragma unroll
    for (int c = 0; c < 5; ++c) q[c] = b2f(qrow[c * 64 + lane]);
    float qw = (lane < 33) ? b2f(qrow[960 + lane]) : 0.f;
    float qwbe = __shfl(qw, 32, 64);
    if (lane >= 32) qw = 0.f;

    float m = -INFINITY, l = 0.f, as = 0.f;
    float av[5] = {0.f, 0.f, 0.f, 0.f, 0.f};
    int e = head[n];
    while (e >= 0) {
        int src = srcArr[e];
        const u16* krow = qkv + (size_t)src * 1024 + 320;
        float eav = (lane < 32) ? b2f(ea[(size_t)e * 32 + lane]) : 0.f;
        float dot = qw * eav;
#pragma unroll
        for (int c = 0; c < 5; ++c) dot += q[c] * b2f(krow[c * 64 + lane]);
#pragma unroll
        for (int off = 32; off > 0; off >>= 1) dot += __shfl_xor(dot, off, 64);
        float alpha = (dot + qwbe) * 0.05590169943749474f;  // 1/sqrt(320)
        float mn = fmaxf(m, alpha);
        float sc = __expf(m - mn);
        float p  = __expf(alpha - mn);
        l = l * sc + p;
        const u16* vrow = krow + 320;
#pragma unroll
        for (int c = 0; c < 5; ++c) av[c] = av[c] * sc + p * b2f(vrow[c * 64 + lane]);
        as = as * sc + p * eav;
        m = mn;
        e = nxt[e];
    }
    if (l > 0.f) {
        float inv = 1.f / l;
        float* arow = acc + (size_t)n * DIM;
#pragma unroll
        for (int c = 0; c < 5; ++c) arow[c * 64 + lane] += av[c] * inv;
        u16 sv = 0;
        if (lane < 32) sv = f2b(as * inv);
        else if (lane == 32) sv = 0x3f80;  // 1.0
        sbuf[(size_t)n * 64 + lane] = sv;
    } else {
        sbuf[(size_t)n * 64 + lane] = 0;
    }
}

// ---------------------------------------------------------------------------
// Post: x_ = lrelu(acc/9); graph layernorm; h = 0.5*(h + x_)  (h in bf16)
// ---------------------------------------------------------------------------
__device__ __forceinline__ int lowerb(const int* a, int n, int v) {
    int lo = 0, hi = n;
    while (lo < hi) { int mid = (lo + hi) >> 1; if (a[mid] < v) lo = mid + 1; else hi = mid; }
    return lo;
}

__global__ __launch_bounds__(1024) void k_post(
    const float* __restrict__ acc, u16* __restrict__ hb,
    const int* __restrict__ batch, const float* __restrict__ gamma,
    const float* __restrict__ beta)
{
    int g = blockIdx.x;
    int start = lowerb(batch, N_NODES, g);
    int end   = lowerb(batch, N_NODES, g + 1);
    int cnt = end - start;
    if (cnt == 0) return;
    size_t i0 = (size_t)start * DIM, i1 = (size_t)end * DIM;

    float s = 0.f, ss = 0.f;
    for (size_t i = i0 + threadIdx.x; i < i1; i += 1024) {
        float v = acc[i] * (1.f / 9.f);
        v = v > 0.f ? v : 0.01f * v;
        s += v; ss += v * v;
    }
    __shared__ float rs[16], rss[16];
#pragma unroll
    for (int off = 32; off > 0; off >>= 1) { s += __shfl_xor(s, off, 64); ss += __shfl_xor(ss, off, 64); }
    int wave = threadIdx.x >> 6, lane = threadIdx.x & 63;
    if (lane == 0) { rs[wave] = s; rss[wave] = ss; }
    __syncthreads();
    if (threadIdx.x == 0) {
        float S = 0.f, SS = 0.f;
        for (int w = 0; w < 16; ++w) { S += rs[w]; SS += rss[w]; }
        float norm = (float)cnt * DIM;
        float mean = S / norm;
        float var = SS / norm - mean * mean;
        rs[0] = mean;
        rss[0] = rsqrtf(var + 1e-5f);
    }
    __syncthreads();
    float mean = rs[0], rsig = rss[0];
    for (size_t i = i0 + threadIdx.x; i < i1; i += 1024) {
        float v = acc[i] * (1.f / 9.f);
        v = v > 0.f ? v : 0.01f * v;
        int c = (int)(i % DIM);
        float o = (v - mean) * rsig * gamma[c] + beta[c];
        float hn = 0.5f * (b2f(hb[i]) + o);
        hb[i] = f2b(hn);
    }
}

__global__ __launch_bounds__(320) void k_maxpool(
    const u16* __restrict__ hb, const int* __restrict__ batch, float* __restrict__ out)
{
    int g = blockIdx.x, c = threadIdx.x;
    int start = lowerb(batch, N_NODES, g);
    int end   = lowerb(batch, N_NODES, g + 1);
    float m = -INFINITY;
    for (int n = start; n < end; ++n) m = fmaxf(m, b2f(hb[(size_t)n * DIM + c]));
    out[(size_t)g * DIM + c] = m;
}

// ---------------------------------------------------------------------------
extern "C" void kernel_launch(void* const* d_in, const int* in_sizes, int n_in,
                              void* d_out, int out_size, void* d_ws, size_t ws_size,
                              hipStream_t stream)
{
    (void)in_sizes; (void)n_in; (void)out_size;
    const float* x     = (const float*)d_in[0];
    const int*   batch = (const int*)d_in[1];
    const int*   eidx  = (const int*)d_in[2];
    const float* eattr = (const float*)d_in[3];
    const float* W1 = (const float*)d_in[4];
    const float* b1 = (const float*)d_in[5];
    const float* W2 = (const float*)d_in[6];
    const float* b2 = (const float*)d_in[7];
    const float* Wq = (const float*)d_in[8];
    const float* bq = (const float*)d_in[9];
    const float* Wk = (const float*)d_in[10];
    const float* bk = (const float*)d_in[11];
    const float* Wv = (const float*)d_in[12];
    const float* bv = (const float*)d_in[13];
    const float* We = (const float*)d_in[14];
    const float* be = (const float*)d_in[15];
    const float* Ws = (const float*)d_in[16];
    const float* bs = (const float*)d_in[17];
    const float* gamma = (const float*)d_in[18];
    const float* beta  = (const float*)d_in[19];
    float* out = (float*)d_out;

    char* base = (char*)d_ws;
    size_t off = 0;
    auto carve = [&](size_t bytes) -> char* {
        char* r = base + off;
        off += (bytes + 255) & ~(size_t)255;
        return r;
    };
    u16*   h_bf16  = (u16*)  carve((size_t)N_NODES * DIM * 2);      // 32.0 MB
    float* acc     = (float*)carve((size_t)N_NODES * DIM * 4);      // 64.0 MB
    u16*   qkv     = (u16*)  carve((size_t)N_NODES * 1024 * 2);     // 102.4 MB
    u16*   sbuf    = (u16*)  carve((size_t)N_NODES * 64 * 2);       // 6.4 MB
    u16*   Anodes  = (u16*)  carve((size_t)N_NODES * 64 * 2);       // 6.4 MB
    int*   head    = (int*)  carve((size_t)NTYP * N_NODES * 4);     // 1.8 MB
    int*   nxt     = (int*)  carve((size_t)NTYP * N_EDGE * 4);      // 5.4 MB
    u16*   BstQkv  = (u16*)  carve((size_t)27 * 40 * 1024 * 8 * 2); // 17.7 MB
    float* biasQkv = (float*)carve((size_t)27 * 1024 * 4);
    u16*   BstSkip = (u16*)  carve((size_t)3 * 40 * 384 * 8 * 2);
    float* biasSkip= (float*)carve((size_t)3 * 384 * 4);
    u16*   BstSWe  = (u16*)  carve((size_t)27 * 8 * 384 * 8 * 2);
    u16*   BstW1   = (u16*)  carve((size_t)40 * 128 * 8 * 2);
    // newEa: big mode = all 9 types resident (86.4 MB); small = 1 type (9.6 MB)
    size_t fixed = off;
    size_t bigBytes   = (size_t)NTYP * N_EDGE * EH * 2;
    size_t smallBytes = (size_t)N_EDGE * EH * 2;
    int bigEa = (ws_size >= fixed + bigBytes + (1u << 20)) ? 1 : 0;
    u16* newEa = (u16*)carve(bigEa ? bigBytes : smallBytes);

    k_init_head<<<(NTYP * N_NODES + 255) / 256, 256, 0, stream>>>(head);
    k_convert_x<<<(N_NODES * DIM + 255) / 256, 256, 0, stream>>>(x, h_bf16);
    k_prep_qkvW<<<(27 * 320 * 1024 + 255) / 256, 256, 0, stream>>>(Wq, Wk, Wv, We, be, BstQkv);
    k_prep_qkvB<<<(27 * 1024 + 255) / 256, 256, 0, stream>>>(bq, bk, bv, We, be, biasQkv);
    k_prep_skipW<<<(3 * 320 * 384 + 255) / 256, 256, 0, stream>>>(Ws, BstSkip);
    k_prep_skipB<<<(3 * 384 + 255) / 256, 256, 0, stream>>>(bs, biasSkip);
    k_prep_sWeW<<<(27 * 64 * 384 + 255) / 256, 256, 0, stream>>>(We, be, BstSWe);
    k_prep_w1W<<<(320 * 128 + 255) / 256, 256, 0, stream>>>(W1, BstW1);
    k_build_lists<<<(NTYP * N_EDGE + 255) / 256, 256, 0, stream>>>(eidx, head, nxt);

    const int mt = (N_NODES + 127) / 128;  // 391
    const int et = (N_EDGE + 255) / 256;   // 586
    // A-nodes = x @ [W1a|W1b] -> [N,64] bf16
    gemm_kernel<<<dim3(mt, 1), 256, 0, stream>>>(h_bf16, DIM, BstW1, nullptr,
                                                 Anodes, nullptr, 64, 64, N_NODES, 128, 40, 0);
    if (bigEa) {
        for (int t = 0; t < NTYP; ++t)
            k_edge_mlp<<<dim3(et), 256, 0, stream>>>(
                Anodes, eidx, eattr, W1, b1, W2, b2, newEa + (size_t)t * N_EDGE * EH, t);
    }

    for (int b = 0; b < NBLK; ++b) {
        // acc = h @ sum_t(Ws) + sum_t(bs)
        gemm_kernel<<<dim3(mt, 3), 256, 0, stream>>>(
            h_bf16, DIM, BstSkip + (size_t)b * 40 * 384 * 8, biasSkip + b * 384,
            nullptr, acc, DIM, DIM, N_NODES, 384, 40, 1);
        for (int t = 0; t < NTYP; ++t) {
            int bt = b * NTYP + t;
            u16* eaT = bigEa ? (newEa + (size_t)t * N_EDGE * EH) : newEa;
            if (!bigEa)
                k_edge_mlp<<<dim3(et), 256, 0, stream>>>(
                    Anodes, eidx, eattr, W1, b1, W2, b2, eaT, t);
            // qkv = h @ [Wq|Wk|Wv|Wq@We^T|Wq@be] -> [N,1024] bf16
            gemm_kernel<<<dim3(mt, 8), 256, 0, stream>>>(
                h_bf16, DIM, BstQkv + (size_t)bt * 40 * 1024 * 8, biasQkv + bt * 1024,
                qkv, nullptr, 1024, 1024, N_NODES, 1024, 40, 0);
            k_attn<<<dim3(N_NODES / 4), 256, 0, stream>>>(
                qkv, head + t * N_NODES, nxt + (size_t)t * N_EDGE,
                eidx + (size_t)(t * 2) * N_EDGE, eaT, acc, sbuf);
            // acc += s_ext @ [We; be]
            gemm_kernel<<<dim3(mt, 3), 256, 0, stream>>>(
                sbuf, 64, BstSWe + (size_t)bt * 8 * 384 * 8, nullptr,
                nullptr, acc, DIM, DIM, N_NODES, 384, 8, 2);
        }
        k_post<<<N_GRAPH, 1024, 0, stream>>>(acc, h_bf16, batch,
                                             gamma + b * DIM, beta + b * DIM);
    }
    k_maxpool<<<N_GRAPH, 320, 0, stream>>>(h_bf16, batch, out);
}

// Round 3
// 6978.350 us; speedup vs baseline: 1.2042x; 1.2042x over previous
//
#include <hip/hip_runtime.h>

#define N_NODES 50000
#define N_EDGE  150000
#define N_GRAPH 200
#define DIM     320
#define EDI     15
#define EH      32
#define NBLK    3
#define NTYP    9
#define NPAD    51200   // per-type CSR stride (50 blocks of 1024)
#define BPT     50      // scan blocks per type
#define QLD     1000    // qkv row stride (993 used cols)

typedef unsigned short u16;
typedef unsigned int   u32;
typedef __bf16 bf16x8 __attribute__((ext_vector_type(8)));
typedef float  f32x4  __attribute__((ext_vector_type(4)));

__device__ __forceinline__ float b2f(u16 s) {
    u32 u = ((u32)s) << 16;
    return __builtin_bit_cast(float, u);
}
__device__ __forceinline__ u16 f2b(float f) {
    u32 u = __builtin_bit_cast(u32, f);
    u = (u + 0x7fffu + ((u >> 16) & 1u)) >> 16;
    return (u16)u;
}
__device__ __forceinline__ void async_copy16(const void* g, void* l) {
    __builtin_amdgcn_global_load_lds(
        (const __attribute__((address_space(1))) unsigned int*)g,
        (__attribute__((address_space(3))) unsigned int*)l, 16, 0, 0);
}

// ---------------------------------------------------------------------------
// bf16 MFMA GEMM, m97-style global_load_lds staging.
// A: kq-major [KQ][Mstride][8] (element (k,m) at ((k>>3)*Mstride + m)*8 + (k&7))
// Bst: same layout with NP cols. K = KQ*8. Tile 128x128, 4 waves, BK=32.
// mode 0: Cb[row*ldc+col] = bf16(v) ; mode 1: Cf[row*ldc+col] = v
// ---------------------------------------------------------------------------
__global__ __launch_bounds__(256) void gemm_kernel(
    const u16* __restrict__ A, int Mstride,
    const u16* __restrict__ Bst, const float* __restrict__ bias,
    u16* __restrict__ Cb, float* __restrict__ Cf,
    int ldc, int out_cols, int M, int NP, int KQ, int mode)
{
    __shared__ u16 As[4 * 128 * 8];   // [q][row][8]  8 KB
    __shared__ u16 Bs[4 * 128 * 8];
    const int tid = threadIdx.x;
    const int wave = tid >> 6, lane = tid & 63;
    const int m0 = blockIdx.x * 128, n0 = blockIdx.y * 128;
    const int wm = (wave & 1) << 6, wn = (wave >> 1) << 6;
    const int lm = lane & 15, quad = lane >> 4;

    f32x4 acc[4][4] = {};
    const int nIter = KQ >> 2;

    for (int it = 0; it < nIter; ++it) {
        const int kq0 = it * 4;
#pragma unroll
        for (int p = 0; p < 2; ++p) {
            int j = wave * 2 + p;          // 0..7
            int q = j >> 1, half = j & 1;
            const u16* ga = A + ((size_t)(kq0 + q) * Mstride + m0 + half * 64 + lane) * 8;
            async_copy16(ga, &As[(size_t)j * 512]);
            const u16* gb = Bst + ((size_t)(kq0 + q) * NP + n0 + half * 64 + lane) * 8;
            async_copy16(gb, &Bs[(size_t)j * 512]);
        }
        __syncthreads();

        bf16x8 af[4], bfr[4];
#pragma unroll
        for (int mi = 0; mi < 4; ++mi)
            af[mi] = __builtin_bit_cast(bf16x8, *(const uint4*)(&As[((size_t)quad * 128 + wm + mi * 16 + lm) * 8]));
#pragma unroll
        for (int ni = 0; ni < 4; ++ni)
            bfr[ni] = __builtin_bit_cast(bf16x8, *(const uint4*)(&Bs[((size_t)quad * 128 + wn + ni * 16 + lm) * 8]));
#pragma unroll
        for (int mi = 0; mi < 4; ++mi)
#pragma unroll
            for (int ni = 0; ni < 4; ++ni)
                acc[mi][ni] = __builtin_amdgcn_mfma_f32_16x16x32_bf16(af[mi], bfr[ni], acc[mi][ni], 0, 0, 0);
        __syncthreads();
    }

    // epilogue: C/D layout col=lane&15, row=quad*4+reg
#pragma unroll
    for (int mi = 0; mi < 4; ++mi) {
        int row = m0 + wm + mi * 16 + quad * 4;
#pragma unroll
        for (int ni = 0; ni < 4; ++ni) {
            int col = n0 + wn + ni * 16 + lm;
            float bv = bias ? bias[col] : 0.f;
#pragma unroll
            for (int r = 0; r < 4; ++r) {
                int rr = row + r;
                if (rr < M && col < out_cols) {
                    float v = acc[mi][ni][r] + bv;
                    size_t off = (size_t)rr * ldc + col;
                    if (mode == 0) Cb[off] = f2b(v);
                    else           Cf[off] = v;
                }
            }
        }
    }
}

// ---------------------------------------------------------------------------
// prep kernels
// ---------------------------------------------------------------------------
__global__ void k_convert_x(const float* __restrict__ x, u16* __restrict__ hb) {
    int i = blockIdx.x * 256 + threadIdx.x;
    if (i >= N_NODES * DIM) return;
    int node = i / DIM, c = i - node * DIM;
    hb[((size_t)(c >> 3) * N_NODES + node) * 8 + (c & 7)] = f2b(x[i]);
}

// copy part of Bst_qkv (cols 0-959 from Wq|Wk|Wv, cols >=993 zero)
__global__ void k_prep_qkvW(const float* __restrict__ Wq, const float* __restrict__ Wk,
                            const float* __restrict__ Wv, u16* __restrict__ Bst) {
    size_t i = (size_t)blockIdx.x * 256 + threadIdx.x;
    if (i >= (size_t)27 * 320 * 1024) return;
    int col = (int)(i & 1023);
    int k   = (int)((i >> 10) % 320);
    int bt  = (int)(i / (320 * 1024));
    float v;
    if (col < 320)       v = Wq[((size_t)bt * 320 + k) * 320 + col];
    else if (col < 640)  v = Wk[((size_t)bt * 320 + k) * 320 + col - 320];
    else if (col < 960)  v = Wv[((size_t)bt * 320 + k) * 320 + col - 640];
    else if (col >= 993) v = 0.f;
    else return;  // 960-992 written by k_prep_ext
    Bst[(((size_t)bt * 40 + (k >> 3)) * 1024 + col) * 8 + (k & 7)] = f2b(v);
}

// ext columns: 960+c = (Wq@We^T) c<32 ; 992 = Wq@be ; plus bias row from bq
__global__ __launch_bounds__(256) void k_prep_ext(
    const float* __restrict__ Wq, const float* __restrict__ bq,
    const float* __restrict__ We, const float* __restrict__ be,
    u16* __restrict__ Bst, float* __restrict__ biasQkv)
{
    __shared__ float WeL[33 * 321];  // rows 0-31 We, row 32 be; stride 321
    int bt = blockIdx.x, kt = blockIdx.y;  // kt 0..10
    for (int i = threadIdx.x; i < 33 * 320; i += 256) {
        int r = i / 320, d = i - r * 320;
        WeL[r * 321 + d] = (r < 32) ? We[((size_t)bt * 32 + r) * 320 + d]
                                    : be[(size_t)bt * 320 + d];
    }
    __syncthreads();
    if (kt < 10) {
        int k  = kt * 32 + (threadIdx.x >> 3);
        int ct = threadIdx.x & 7;
        const float* wq = Wq + ((size_t)bt * 320 + k) * 320;
        float dot[5] = {0.f, 0.f, 0.f, 0.f, 0.f};
        for (int d = 0; d < 320; ++d) {
            float w = wq[d];
            dot[0] += w * WeL[ct * 321 + d];
            dot[1] += w * WeL[(ct + 8) * 321 + d];
            dot[2] += w * WeL[(ct + 16) * 321 + d];
            dot[3] += w * WeL[(ct + 24) * 321 + d];
            dot[4] += w * WeL[32 * 321 + d];
        }
#pragma unroll
        for (int u = 0; u < 4; ++u)
            Bst[(((size_t)bt * 40 + (k >> 3)) * 1024 + 960 + ct + u * 8) * 8 + (k & 7)] = f2b(dot[u]);
        if (ct == 0)
            Bst[(((size_t)bt * 40 + (k >> 3)) * 1024 + 992) * 8 + (k & 7)] = f2b(dot[4]);
    } else {
        int c = threadIdx.x;
        if (c < 33) {
            const float* b = bq + (size_t)bt * 320;
            float s = 0.f;
            for (int d = 0; d < 320; ++d) s += b[d] * WeL[c * 321 + d];
            biasQkv[bt * 1024 + 960 + c] = s;
        }
    }
}

__global__ void k_prep_qkvB(const float* __restrict__ bq, const float* __restrict__ bk,
                            const float* __restrict__ bv, float* __restrict__ bias) {
    int i = blockIdx.x * 256 + threadIdx.x;
    if (i >= 27 * 1024) return;
    int col = i & 1023, bt = i >> 10;
    float v;
    if (col < 320)       v = bq[bt * 320 + col];
    else if (col < 640)  v = bk[bt * 320 + col - 320];
    else if (col < 960)  v = bv[bt * 320 + col - 640];
    else if (col >= 993) v = 0.f;
    else return;  // ext
    bias[i] = v;
}

__global__ void k_prep_skipW(const float* __restrict__ Ws, u16* __restrict__ Bst) {
    int i = blockIdx.x * 256 + threadIdx.x;
    if (i >= 3 * 320 * 384) return;
    int col = i % 384, k = (i / 384) % 320, b = i / (384 * 320);
    float v = 0.f;
    if (col < 320)
        for (int t = 0; t < 9; ++t)
            v += Ws[((size_t)(b * 9 + t) * 320 + k) * 320 + col];
    Bst[(((size_t)b * 40 + (k >> 3)) * 384 + col) * 8 + (k & 7)] = f2b(v);
}
__global__ void k_prep_skipB(const float* __restrict__ bs, float* __restrict__ bias) {
    int i = blockIdx.x * 256 + threadIdx.x;
    if (i >= 3 * 384) return;
    int col = i % 384, b = i / 384;
    float v = 0.f;
    if (col < 320)
        for (int t = 0; t < 9; ++t) v += bs[(b * 9 + t) * 320 + col];
    bias[i] = v;
}

__global__ void k_prep_w1W(const float* __restrict__ W1, u16* __restrict__ Bst) {
    int i = blockIdx.x * 256 + threadIdx.x;
    if (i >= 320 * 128) return;
    int col = i & 127, k = i >> 7;
    float v = 0.f;
    if (col < 32)      v = W1[(size_t)k * 32 + col];
    else if (col < 64) v = W1[(size_t)(320 + k) * 32 + (col - 32)];
    Bst[((size_t)(k >> 3) * 128 + col) * 8 + (k & 7)] = f2b(v);
}

// ---------------------------------------------------------------------------
// CSR build: count -> scan (3 kernels) -> scatter. cnt doubles as cursor.
// ---------------------------------------------------------------------------
__global__ void k_csr_zero(int* __restrict__ cnt) {
    int i = blockIdx.x * 256 + threadIdx.x;
    if (i < NTYP * NPAD) cnt[i] = 0;
}
__global__ void k_csr_count(const int* __restrict__ eidx, int* __restrict__ cnt) {
    int i = blockIdx.x * 256 + threadIdx.x;
    if (i >= NTYP * N_EDGE) return;
    int t = i / N_EDGE, e = i - t * N_EDGE;
    int dst = eidx[(size_t)(t * 2 + 1) * N_EDGE + e];
    atomicAdd(&cnt[t * NPAD + dst], 1);
}
__global__ __launch_bounds__(1024) void k_csr_scan1(const int* __restrict__ cnt,
                                                    int* __restrict__ rowStart,
                                                    int* __restrict__ blockSum) {
    __shared__ int tmp[1024];
    int t = blockIdx.y, blk = blockIdx.x, tid = threadIdx.x;
    int idx = t * NPAD + blk * 1024 + tid;
    int v = cnt[idx];
    tmp[tid] = v;
    __syncthreads();
    for (int off = 1; off < 1024; off <<= 1) {
        int x = (tid >= off) ? tmp[tid - off] : 0;
        __syncthreads();
        tmp[tid] += x;
        __syncthreads();
    }
    rowStart[idx] = tmp[tid] - v;
    if (tid == 1023) blockSum[t * 64 + blk] = tmp[tid];
}
__global__ void k_csr_scan2(int* __restrict__ blockSum) {
    int t = threadIdx.x;
    if (t >= NTYP) return;
    int run = 0;
    for (int b = 0; b < BPT; ++b) {
        int v = blockSum[t * 64 + b];
        blockSum[t * 64 + b] = run;
        run += v;
    }
}
__global__ void k_csr_scan3(int* __restrict__ rowStart, const int* __restrict__ blockSum,
                            int* __restrict__ cursor) {
    int i = blockIdx.x * 256 + threadIdx.x;
    if (i >= NTYP * NPAD) return;
    int t = i / NPAD, n = i - t * NPAD;
    int v = rowStart[i] + blockSum[t * 64 + (n >> 10)];
    rowStart[i] = v;
    cursor[i] = v;
}
__global__ void k_csr_scatter(const int* __restrict__ eidx, int* __restrict__ cursor,
                              u16* __restrict__ sSrc, int* __restrict__ sEid) {
    int i = blockIdx.x * 256 + threadIdx.x;
    if (i >= NTYP * N_EDGE) return;
    int t = i / N_EDGE, e = i - t * N_EDGE;
    int src = eidx[(size_t)(t * 2) * N_EDGE + e];
    int dst = eidx[(size_t)(t * 2 + 1) * N_EDGE + e];
    int pos = atomicAdd(&cursor[t * NPAD + dst], 1);
    sSrc[(size_t)t * N_EDGE + pos] = (u16)src;
    sEid[(size_t)t * N_EDGE + pos] = e;
}

// ---------------------------------------------------------------------------
// Edge MLP for one type t
// ---------------------------------------------------------------------------
__global__ __launch_bounds__(256) void k_edge_mlp(
    const u16* __restrict__ Anodes, const int* __restrict__ eidx,
    const float* __restrict__ eattr, const float* __restrict__ W1,
    const float* __restrict__ b1, const float* __restrict__ W2,
    const float* __restrict__ b2, u16* __restrict__ outEa, int t)
{
    __shared__ float w1c[EDI][EH];
    __shared__ float w2s[EH][EH];
    __shared__ float b1s[EH], b2s[EH];
    int tid = threadIdx.x;
    for (int i = tid; i < EDI * EH; i += 256) w1c[i / EH][i % EH] = W1[(640 + i / EH) * EH + (i % EH)];
    for (int i = tid; i < EH * EH; i += 256) w2s[i / EH][i % EH] = W2[i];
    if (tid < EH) { b1s[tid] = b1[tid]; b2s[tid] = b2[tid]; }
    __syncthreads();

    int e = blockIdx.x * 256 + tid;
    if (e >= N_EDGE) return;
    int src = eidx[(size_t)(t * 2) * N_EDGE + e];
    int dst = eidx[(size_t)(t * 2 + 1) * N_EDGE + e];
    const float* eat = eattr + ((size_t)t * N_EDGE + e) * EDI;
    const u16* a1 = Anodes + (size_t)src * 64;
    const u16* a2 = Anodes + (size_t)dst * 64 + 32;

    float h1[EH];
#pragma unroll
    for (int j = 0; j < EH; ++j) h1[j] = b2f(a1[j]) + b2f(a2[j]) + b1s[j];
    for (int i = 0; i < EDI; ++i) {
        float v = eat[i];
#pragma unroll
        for (int j = 0; j < EH; ++j) h1[j] += v * w1c[i][j];
    }
#pragma unroll
    for (int j = 0; j < EH; ++j) h1[j] = h1[j] > 0.f ? h1[j] : 0.01f * h1[j];

    u16* orow = outEa + (size_t)e * EH;
    for (int j = 0; j < EH; ++j) {
        float o = b2s[j];
#pragma unroll
        for (int i = 0; i < EH; ++i) o += h1[i] * w2s[i][j];
        orow[j] = f2b(o);
    }
}

// ---------------------------------------------------------------------------
// Attention: one wave per dst node, CSR edge range, online softmax, unroll x2.
// Epilogue folds acc[n] += av/l + (s@We + be).
// ---------------------------------------------------------------------------
__global__ __launch_bounds__(256) void k_attn(
    const u16* __restrict__ qkv, const int* __restrict__ rowStart,
    const u16* __restrict__ sSrc, const int* __restrict__ sEid,
    const u16* __restrict__ ea, const float* __restrict__ We,
    const float* __restrict__ be, float* __restrict__ acc)
{
    int wave = threadIdx.x >> 6, lane = threadIdx.x & 63;
    int n = blockIdx.x * 4 + wave;
    if (n >= N_NODES) return;
    int eb = rowStart[n], ee = rowStart[n + 1];
    if (eb == ee) return;

    const u16* qrow = qkv + (size_t)n * QLD;
    float q[5];
#pragma unroll
    for (int c = 0; c < 5; ++c) q[c] = b2f(qrow[c * 64 + lane]);
    float qwl = (lane < 33) ? b2f(qrow[960 + lane]) : 0.f;
    float qwbe = __shfl(qwl, 32, 64);
    float qw = (lane < 32) ? qwl : 0.f;
    const float RS = 0.05590169943749474f;  // 1/sqrt(320)

    float m = -INFINITY, l = 0.f, as = 0.f;
    float av[5] = {0.f, 0.f, 0.f, 0.f, 0.f};

    int ei = eb;
    for (; ei + 2 <= ee; ei += 2) {
        int s0 = sSrc[ei], s1 = sSrc[ei + 1];
        int id0 = sEid[ei], id1 = sEid[ei + 1];
        const u16* k0 = qkv + (size_t)s0 * QLD + 320;
        const u16* k1 = qkv + (size_t)s1 * QLD + 320;
        float ea0 = (lane < 32) ? b2f(ea[(size_t)id0 * 32 + lane]) : 0.f;
        float ea1 = (lane < 32) ? b2f(ea[(size_t)id1 * 32 + lane]) : 0.f;
        float d0 = qw * ea0, d1 = qw * ea1;
#pragma unroll
        for (int c = 0; c < 5; ++c) {
            d0 += q[c] * b2f(k0[c * 64 + lane]);
            d1 += q[c] * b2f(k1[c * 64 + lane]);
        }
#pragma unroll
        for (int off = 32; off > 0; off >>= 1) {
            d0 += __shfl_xor(d0, off, 64);
            d1 += __shfl_xor(d1, off, 64);
        }
        float a0 = (d0 + qwbe) * RS, a1 = (d1 + qwbe) * RS;
        float mn = fmaxf(m, fmaxf(a0, a1));
        float sc = __expf(m - mn);
        float p0 = __expf(a0 - mn), p1 = __expf(a1 - mn);
        l = l * sc + p0 + p1;
        const u16* v0 = k0 + 320;
        const u16* v1 = k1 + 320;
#pragma unroll
        for (int c = 0; c < 5; ++c)
            av[c] = av[c] * sc + p0 * b2f(v0[c * 64 + lane]) + p1 * b2f(v1[c * 64 + lane]);
        as = as * sc + p0 * ea0 + p1 * ea1;
        m = mn;
    }
    if (ei < ee) {
        int s0 = sSrc[ei];
        int id0 = sEid[ei];
        const u16* k0 = qkv + (size_t)s0 * QLD + 320;
        float ea0 = (lane < 32) ? b2f(ea[(size_t)id0 * 32 + lane]) : 0.f;
        float d0 = qw * ea0;
#pragma unroll
        for (int c = 0; c < 5; ++c) d0 += q[c] * b2f(k0[c * 64 + lane]);
#pragma unroll
        for (int off = 32; off > 0; off >>= 1) d0 += __shfl_xor(d0, off, 64);
        float a0 = (d0 + qwbe) * RS;
        float mn = fmaxf(m, a0);
        float sc = __expf(m - mn), p0 = __expf(a0 - mn);
        l = l * sc + p0;
        const u16* v0 = k0 + 320;
#pragma unroll
        for (int c = 0; c < 5; ++c) av[c] = av[c] * sc + p0 * b2f(v0[c * 64 + lane]);
        as = as * sc + p0 * ea0;
    }

    float inv = 1.f / l;
    float sval = as * inv;   // lane j<32 holds s_j
    float o[5];
#pragma unroll
    for (int cj = 0; cj < 5; ++cj) o[cj] = av[cj] * inv + be[cj * 64 + lane];
    for (int j = 0; j < 32; ++j) {
        float sj = __shfl(sval, j, 64);
        const float* wrow = We + (size_t)j * DIM;
#pragma unroll
        for (int cj = 0; cj < 5; ++cj) o[cj] += sj * wrow[cj * 64 + lane];
    }
    float* arow = acc + (size_t)n * DIM;
#pragma unroll
    for (int cj = 0; cj < 5; ++cj) arow[cj * 64 + lane] += o[cj];
}

// ---------------------------------------------------------------------------
// Post: x_ = lrelu(acc/9); graph layernorm; h = 0.5*(h + x_) (h kq-major bf16)
// ---------------------------------------------------------------------------
__device__ __forceinline__ int lowerb(const int* a, int n, int v) {
    int lo = 0, hi = n;
    while (lo < hi) { int mid = (lo + hi) >> 1; if (a[mid] < v) lo = mid + 1; else hi = mid; }
    return lo;
}

__global__ __launch_bounds__(1024) void k_post(
    const float* __restrict__ acc, u16* __restrict__ hb,
    const int* __restrict__ batch, const float* __restrict__ gamma,
    const float* __restrict__ beta)
{
    int g = blockIdx.x;
    int start = lowerb(batch, N_NODES, g);
    int end   = lowerb(batch, N_NODES, g + 1);
    int cnt = end - start;
    if (cnt == 0) return;
    int i0 = start * DIM, i1 = end * DIM;

    float s = 0.f, ss = 0.f;
    for (int i = i0 + threadIdx.x; i < i1; i += 1024) {
        float v = acc[i] * (1.f / 9.f);
        v = v > 0.f ? v : 0.01f * v;
        s += v; ss += v * v;
    }
    __shared__ float rs[16], rss[16];
#pragma unroll
    for (int off = 32; off > 0; off >>= 1) { s += __shfl_xor(s, off, 64); ss += __shfl_xor(ss, off, 64); }
    int wave = threadIdx.x >> 6, lane = threadIdx.x & 63;
    if (lane == 0) { rs[wave] = s; rss[wave] = ss; }
    __syncthreads();
    if (threadIdx.x == 0) {
        float S = 0.f, SS = 0.f;
        for (int w = 0; w < 16; ++w) { S += rs[w]; SS += rss[w]; }
        float norm = (float)cnt * DIM;
        float mean = S / norm;
        float var = SS / norm - mean * mean;
        rs[0] = mean;
        rss[0] = rsqrtf(var + 1e-5f);
    }
    __syncthreads();
    float mean = rs[0], rsig = rss[0];
    for (int i = i0 + threadIdx.x; i < i1; i += 1024) {
        float v = acc[i] * (1.f / 9.f);
        v = v > 0.f ? v : 0.01f * v;
        int node = i / DIM, c = i - node * DIM;
        float o = (v - mean) * rsig * gamma[c] + beta[c];
        size_t hidx = ((size_t)(c >> 3) * N_NODES + node) * 8 + (c & 7);
        hb[hidx] = f2b(0.5f * (b2f(hb[hidx]) + o));
    }
}

__global__ __launch_bounds__(320) void k_maxpool(
    const u16* __restrict__ hb, const int* __restrict__ batch, float* __restrict__ out)
{
    int g = blockIdx.x, c = threadIdx.x;
    int start = lowerb(batch, N_NODES, g);
    int end   = lowerb(batch, N_NODES, g + 1);
    size_t base = (size_t)(c >> 3) * N_NODES * 8 + (c & 7);
    float m = -INFINITY;
    for (int n = start; n < end; ++n) m = fmaxf(m, b2f(hb[base + (size_t)n * 8]));
    out[(size_t)g * DIM + c] = m;
}

// ---------------------------------------------------------------------------
extern "C" void kernel_launch(void* const* d_in, const int* in_sizes, int n_in,
                              void* d_out, int out_size, void* d_ws, size_t ws_size,
                              hipStream_t stream)
{
    (void)in_sizes; (void)n_in; (void)out_size;
    const float* x     = (const float*)d_in[0];
    const int*   batch = (const int*)d_in[1];
    const int*   eidx  = (const int*)d_in[2];
    const float* eattr = (const float*)d_in[3];
    const float* W1 = (const float*)d_in[4];
    const float* b1 = (const float*)d_in[5];
    const float* W2 = (const float*)d_in[6];
    const float* b2 = (const float*)d_in[7];
    const float* Wq = (const float*)d_in[8];
    const float* bq = (const float*)d_in[9];
    const float* Wk = (const float*)d_in[10];
    const float* bk = (const float*)d_in[11];
    const float* Wv = (const float*)d_in[12];
    const float* bv = (const float*)d_in[13];
    const float* We = (const float*)d_in[14];
    const float* be = (const float*)d_in[15];
    const float* Ws = (const float*)d_in[16];
    const float* bs = (const float*)d_in[17];
    const float* gamma = (const float*)d_in[18];
    const float* beta  = (const float*)d_in[19];
    float* out = (float*)d_out;

    char* base = (char*)d_ws;
    size_t off = 0;
    auto carve = [&](size_t bytes) -> char* {
        char* r = base + off;
        off += (bytes + 255) & ~(size_t)255;
        return r;
    };
    u16*   hbKq    = (u16*)  carve((size_t)40 * N_NODES * 8 * 2 + 1024);  // 32 MB (+pad for M-tail reads)
    float* acc     = (float*)carve((size_t)N_NODES * DIM * 4);            // 64 MB
    u16*   qkv     = (u16*)  carve((size_t)N_NODES * QLD * 2);            // 100 MB
    u16*   Anodes  = (u16*)  carve((size_t)N_NODES * 64 * 2);             // 6.4 MB
    u16*   BstQkv  = (u16*)  carve((size_t)27 * 40 * 1024 * 8 * 2);       // 17.7 MB
    float* biasQkv = (float*)carve((size_t)27 * 1024 * 4);
    u16*   BstSkip = (u16*)  carve((size_t)3 * 40 * 384 * 8 * 2);
    float* biasSkip= (float*)carve((size_t)3 * 384 * 4);
    u16*   BstW1   = (u16*)  carve((size_t)40 * 128 * 8 * 2);
    int*   cnt     = (int*)  carve((size_t)NTYP * NPAD * 4);              // also cursor
    int*   rowStart= (int*)  carve((size_t)NTYP * NPAD * 4);
    int*   blockSum= (int*)  carve((size_t)NTYP * 64 * 4);
    u16*   sSrc    = (u16*)  carve((size_t)NTYP * N_EDGE * 2);
    int*   sEid    = (int*)  carve((size_t)NTYP * N_EDGE * 4);
    size_t fixed = off;
    size_t bigBytes   = (size_t)NTYP * N_EDGE * EH * 2;
    size_t smallBytes = (size_t)N_EDGE * EH * 2;
    int bigEa = (ws_size >= fixed + bigBytes + (1u << 20)) ? 1 : 0;
    u16* newEa = (u16*)carve(bigEa ? bigBytes : smallBytes);

    // prep
    k_convert_x<<<(N_NODES * DIM + 255) / 256, 256, 0, stream>>>(x, hbKq);
    k_prep_qkvW<<<(27 * 320 * 1024 + 255) / 256, 256, 0, stream>>>(Wq, Wk, Wv, BstQkv);
    k_prep_ext<<<dim3(27, 11), 256, 0, stream>>>(Wq, bq, We, be, BstQkv, biasQkv);
    k_prep_qkvB<<<(27 * 1024 + 255) / 256, 256, 0, stream>>>(bq, bk, bv, biasQkv);
    k_prep_skipW<<<(3 * 320 * 384 + 255) / 256, 256, 0, stream>>>(Ws, BstSkip);
    k_prep_skipB<<<(3 * 384 + 255) / 256, 256, 0, stream>>>(bs, biasSkip);
    k_prep_w1W<<<(320 * 128 + 255) / 256, 256, 0, stream>>>(W1, BstW1);

    // CSR
    k_csr_zero<<<(NTYP * NPAD + 255) / 256, 256, 0, stream>>>(cnt);
    k_csr_count<<<(NTYP * N_EDGE + 255) / 256, 256, 0, stream>>>(eidx, cnt);
    k_csr_scan1<<<dim3(BPT, NTYP), 1024, 0, stream>>>(cnt, rowStart, blockSum);
    k_csr_scan2<<<1, 64, 0, stream>>>(blockSum);
    k_csr_scan3<<<(NTYP * NPAD + 255) / 256, 256, 0, stream>>>(rowStart, blockSum, cnt);
    k_csr_scatter<<<(NTYP * N_EDGE + 255) / 256, 256, 0, stream>>>(eidx, cnt, sSrc, sEid);

    const int mt = (N_NODES + 127) / 128;  // 391
    const int et = (N_EDGE + 255) / 256;
    // Anodes = x @ [W1a|W1b]
    gemm_kernel<<<dim3(mt, 1), 256, 0, stream>>>(hbKq, N_NODES, BstW1, nullptr,
                                                 Anodes, nullptr, 64, 64, N_NODES, 128, 40, 0);
    if (bigEa) {
        for (int t = 0; t < NTYP; ++t)
            k_edge_mlp<<<dim3(et), 256, 0, stream>>>(
                Anodes, eidx, eattr, W1, b1, W2, b2, newEa + (size_t)t * N_EDGE * EH, t);
    }

    for (int b = 0; b < NBLK; ++b) {
        gemm_kernel<<<dim3(mt, 3), 256, 0, stream>>>(
            hbKq, N_NODES, BstSkip + (size_t)b * 40 * 384 * 8, biasSkip + b * 384,
            nullptr, acc, DIM, DIM, N_NODES, 384, 40, 1);
        for (int t = 0; t < NTYP; ++t) {
            int bt = b * NTYP + t;
            u16* eaT = bigEa ? (newEa + (size_t)t * N_EDGE * EH) : newEa;
            if (!bigEa)
                k_edge_mlp<<<dim3(et), 256, 0, stream>>>(
                    Anodes, eidx, eattr, W1, b1, W2, b2, eaT, t);
            gemm_kernel<<<dim3(mt, 8), 256, 0, stream>>>(
                hbKq, N_NODES, BstQkv + (size_t)bt * 40 * 1024 * 8, biasQkv + bt * 1024,
                qkv, nullptr, QLD, 993, N_NODES, 1024, 40, 0);
            k_attn<<<dim3((N_NODES + 3) / 4), 256, 0, stream>>>(
                qkv, rowStart + t * NPAD, sSrc + (size_t)t * N_EDGE, sEid + (size_t)t * N_EDGE,
                eaT, We + (size_t)bt * EH * DIM, be + (size_t)bt * DIM, acc);
        }
        k_post<<<N_GRAPH, 1024, 0, stream>>>(acc, hbKq, batch,
                                             gamma + b * DIM, beta + b * DIM);
    }
    k_maxpool<<<N_GRAPH, 320, 0, stream>>>(hbKq, batch, out);
}

// Round 4
// 6247.927 us; speedup vs baseline: 1.3450x; 1.1169x over previous
//
#include <hip/hip_runtime.h>

#define N_NODES 50000
#define N_EDGE  150000
#define N_GRAPH 200
#define DIM     320
#define EDI     15
#define EH      32
#define NBLK    3
#define NTYP    9
#define NPAD    51200   // per-type CSR stride (50 blocks of 1024)
#define BPT     50      // scan blocks per type
#define QLD     1000    // qkv row stride (993 used cols)

typedef unsigned short u16;
typedef unsigned int   u32;
typedef __bf16 bf16x8 __attribute__((ext_vector_type(8)));
typedef float  f32x4  __attribute__((ext_vector_type(4)));

__device__ __forceinline__ float b2f(u16 s) {
    u32 u = ((u32)s) << 16;
    return __builtin_bit_cast(float, u);
}
__device__ __forceinline__ u16 f2b(float f) {
    u32 u = __builtin_bit_cast(u32, f);
    u = (u + 0x7fffu + ((u >> 16) & 1u)) >> 16;
    return (u16)u;
}
__device__ __forceinline__ bf16x8 ldfrag(const u16* p) {
    return __builtin_bit_cast(bf16x8, *(const uint4*)p);
}

// ---------------------------------------------------------------------------
// bf16 MFMA GEMM — NO LDS, NO BARRIERS. Both operands pre-staged kq-major:
// element (k, m) at ((k>>3)*Stride + m)*8 + (k&7)  ->  every MFMA fragment is
// a contiguous, lane-coalesced 16B global load. Software-pipelined K-loop.
// grid: x = col tiles (fastest -> A slab L2-hot), y = row tiles.
// Tile 128x128, 4 waves of 64x64. mode 0: Cb=bf16 ; 1: Cf=f32 ; 2: Cf += f32
// ---------------------------------------------------------------------------
__global__ __launch_bounds__(256) void gemm_kernel(
    const u16* __restrict__ A, int Mstride,
    const u16* __restrict__ Bst, const float* __restrict__ bias,
    u16* __restrict__ Cb, float* __restrict__ Cf,
    int ldc, int out_cols, int M, int NP, int KQ, int mode)
{
    const int tid = threadIdx.x;
    const int wave = tid >> 6, lane = tid & 63;
    const int n0 = blockIdx.x * 128, m0 = blockIdx.y * 128;
    const int wm = (wave & 1) << 6, wn = (wave >> 1) << 6;
    const int lm = lane & 15, quad = lane >> 4;

    const u16* aBase = A + ((size_t)quad * Mstride + m0 + wm + lm) * 8;
    const u16* bBase = Bst + ((size_t)quad * NP + n0 + wn + lm) * 8;
    const size_t aK = (size_t)4 * Mstride * 8;   // advance 4 chunks (K=32)
    const size_t bK = (size_t)4 * NP * 8;

    f32x4 acc[4][4] = {};
    const int nIter = KQ >> 2;

    bf16x8 af[4], bfr[4];
#pragma unroll
    for (int mi = 0; mi < 4; ++mi) af[mi] = ldfrag(aBase + mi * 128);
#pragma unroll
    for (int ni = 0; ni < 4; ++ni) bfr[ni] = ldfrag(bBase + ni * 128);

    for (int it = 0; it < nIter - 1; ++it) {
        bf16x8 afn[4], bfn[4];
        const u16* an = aBase + (size_t)(it + 1) * aK;
        const u16* bn = bBase + (size_t)(it + 1) * bK;
#pragma unroll
        for (int mi = 0; mi < 4; ++mi) afn[mi] = ldfrag(an + mi * 128);
#pragma unroll
        for (int ni = 0; ni < 4; ++ni) bfn[ni] = ldfrag(bn + ni * 128);
#pragma unroll
        for (int mi = 0; mi < 4; ++mi)
#pragma unroll
            for (int ni = 0; ni < 4; ++ni)
                acc[mi][ni] = __builtin_amdgcn_mfma_f32_16x16x32_bf16(af[mi], bfr[ni], acc[mi][ni], 0, 0, 0);
#pragma unroll
        for (int i = 0; i < 4; ++i) { af[i] = afn[i]; bfr[i] = bfn[i]; }
    }
#pragma unroll
    for (int mi = 0; mi < 4; ++mi)
#pragma unroll
        for (int ni = 0; ni < 4; ++ni)
            acc[mi][ni] = __builtin_amdgcn_mfma_f32_16x16x32_bf16(af[mi], bfr[ni], acc[mi][ni], 0, 0, 0);

    // epilogue: C/D layout col=lane&15, row=quad*4+reg
#pragma unroll
    for (int mi = 0; mi < 4; ++mi) {
        int row = m0 + wm + mi * 16 + quad * 4;
#pragma unroll
        for (int ni = 0; ni < 4; ++ni) {
            int col = n0 + wn + ni * 16 + lm;
            float bv = bias ? bias[col] : 0.f;
#pragma unroll
            for (int r = 0; r < 4; ++r) {
                int rr = row + r;
                if (rr < M && col < out_cols) {
                    float v = acc[mi][ni][r] + bv;
                    size_t off = (size_t)rr * ldc + col;
                    if (mode == 0)      Cb[off] = f2b(v);
                    else if (mode == 1) Cf[off] = v;
                    else                Cf[off] += v;
                }
            }
        }
    }
}

// ---------------------------------------------------------------------------
// prep kernels
// ---------------------------------------------------------------------------
__global__ void k_convert_x(const float* __restrict__ x, u16* __restrict__ hb) {
    int i = blockIdx.x * 256 + threadIdx.x;
    if (i >= N_NODES * DIM) return;
    int node = i / DIM, c = i - node * DIM;
    hb[((size_t)(c >> 3) * N_NODES + node) * 8 + (c & 7)] = f2b(x[i]);
}

// Bst_qkv cols 0-959 from Wq|Wk|Wv, cols >=993 zero. Coalesced uint4 writes.
__global__ void k_prep_qkvW(const float* __restrict__ Wq, const float* __restrict__ Wk,
                            const float* __restrict__ Wv, u16* __restrict__ Bst) {
    int i = blockIdx.x * 256 + threadIdx.x;
    if (i >= 27 * 40 * 1024) return;
    int col = i & 1023, kq = (i >> 10) % 40, bt = i / (40 * 1024);
    if (col >= 960 && col < 993) return;  // ext cols written by k_prep_ext
    u16 tmp[8];
    if (col >= 993) {
#pragma unroll
        for (int r = 0; r < 8; ++r) tmp[r] = 0;
    } else {
        const float* W; int c;
        if (col < 320)      { W = Wq; c = col; }
        else if (col < 640) { W = Wk; c = col - 320; }
        else                { W = Wv; c = col - 640; }
#pragma unroll
        for (int r = 0; r < 8; ++r)
            tmp[r] = f2b(W[((size_t)bt * 320 + kq * 8 + r) * 320 + c]);
    }
    *(uint4*)(&Bst[(((size_t)bt * 40 + kq) * 1024 + col) * 8]) = *(uint4*)tmp;
}

// ext columns: 960+c = (Wq@We^T) c<32 ; 992 = Wq@be ; plus bias from bq
__global__ __launch_bounds__(256) void k_prep_ext(
    const float* __restrict__ Wq, const float* __restrict__ bq,
    const float* __restrict__ We, const float* __restrict__ be,
    u16* __restrict__ Bst, float* __restrict__ biasQkv)
{
    __shared__ float WeL[33 * 321];
    int bt = blockIdx.x, kt = blockIdx.y;  // kt 0..10
    for (int i = threadIdx.x; i < 33 * 320; i += 256) {
        int r = i / 320, d = i - r * 320;
        WeL[r * 321 + d] = (r < 32) ? We[((size_t)bt * 32 + r) * 320 + d]
                                    : be[(size_t)bt * 320 + d];
    }
    __syncthreads();
    if (kt < 10) {
        int k  = kt * 32 + (threadIdx.x >> 3);
        int ct = threadIdx.x & 7;
        const float* wq = Wq + ((size_t)bt * 320 + k) * 320;
        float dot[5] = {0.f, 0.f, 0.f, 0.f, 0.f};
        for (int d = 0; d < 320; ++d) {
            float w = wq[d];
            dot[0] += w * WeL[ct * 321 + d];
            dot[1] += w * WeL[(ct + 8) * 321 + d];
            dot[2] += w * WeL[(ct + 16) * 321 + d];
            dot[3] += w * WeL[(ct + 24) * 321 + d];
            dot[4] += w * WeL[32 * 321 + d];
        }
#pragma unroll
        for (int u = 0; u < 4; ++u)
            Bst[(((size_t)bt * 40 + (k >> 3)) * 1024 + 960 + ct + u * 8) * 8 + (k & 7)] = f2b(dot[u]);
        if (ct == 0)
            Bst[(((size_t)bt * 40 + (k >> 3)) * 1024 + 992) * 8 + (k & 7)] = f2b(dot[4]);
    } else {
        int c = threadIdx.x;
        if (c < 33) {
            const float* b = bq + (size_t)bt * 320;
            float s = 0.f;
            for (int d = 0; d < 320; ++d) s += b[d] * WeL[c * 321 + d];
            biasQkv[bt * 1024 + 960 + c] = s;
        }
    }
}

__global__ void k_prep_qkvB(const float* __restrict__ bq, const float* __restrict__ bk,
                            const float* __restrict__ bv, float* __restrict__ bias) {
    int i = blockIdx.x * 256 + threadIdx.x;
    if (i >= 27 * 1024) return;
    int col = i & 1023, bt = i >> 10;
    float v;
    if (col < 320)       v = bq[bt * 320 + col];
    else if (col < 640)  v = bk[bt * 320 + col - 320];
    else if (col < 960)  v = bv[bt * 320 + col - 640];
    else if (col >= 993) v = 0.f;
    else return;  // ext
    bias[i] = v;
}

__global__ void k_prep_skipW(const float* __restrict__ Ws, u16* __restrict__ Bst) {
    int i = blockIdx.x * 256 + threadIdx.x;
    if (i >= 3 * 320 * 384) return;
    int col = i % 384, k = (i / 384) % 320, b = i / (384 * 320);
    float v = 0.f;
    if (col < 320)
        for (int t = 0; t < 9; ++t)
            v += Ws[((size_t)(b * 9 + t) * 320 + k) * 320 + col];
    Bst[(((size_t)b * 40 + (k >> 3)) * 384 + col) * 8 + (k & 7)] = f2b(v);
}
__global__ void k_prep_skipB(const float* __restrict__ bs, float* __restrict__ bias) {
    int i = blockIdx.x * 256 + threadIdx.x;
    if (i >= 3 * 384) return;
    int col = i % 384, b = i / 384;
    float v = 0.f;
    if (col < 320)
        for (int t = 0; t < 9; ++t) v += bs[(b * 9 + t) * 320 + col];
    bias[i] = v;
}

// We_all for batched s-GEMM: K rows k=t*34+j ; j<32 -> We[b*9+t][j], j==32 -> be,
// j==33 / k>=306 / col>=320 -> 0.  Layout [3][40][384][8].
__global__ void k_prep_sWe(const float* __restrict__ We, const float* __restrict__ be,
                           u16* __restrict__ Bst) {
    int i = blockIdx.x * 256 + threadIdx.x;
    if (i >= 3 * 40 * 384) return;
    int col = i % 384, kq = (i / 384) % 40, b = i / (384 * 40);
    u16 tmp[8];
#pragma unroll
    for (int r = 0; r < 8; ++r) {
        int k = kq * 8 + r;
        float v = 0.f;
        if (col < 320 && k < 306) {
            int t = k / 34, j = k - t * 34;
            int bt = b * 9 + t;
            if (j < 32)       v = We[((size_t)bt * 32 + j) * 320 + col];
            else if (j == 32) v = be[(size_t)bt * 320 + col];
        }
        tmp[r] = f2b(v);
    }
    *(uint4*)(&Bst[(((size_t)b * 40 + kq) * 384 + col) * 8]) = *(uint4*)tmp;
}

__global__ void k_prep_w1W(const float* __restrict__ W1, u16* __restrict__ Bst) {
    int i = blockIdx.x * 256 + threadIdx.x;
    if (i >= 320 * 128) return;
    int col = i & 127, k = i >> 7;
    float v = 0.f;
    if (col < 32)      v = W1[(size_t)k * 32 + col];
    else if (col < 64) v = W1[(size_t)(320 + k) * 32 + (col - 32)];
    Bst[((size_t)(k >> 3) * 128 + col) * 8 + (k & 7)] = f2b(v);
}

// ---------------------------------------------------------------------------
// CSR build
// ---------------------------------------------------------------------------
__global__ void k_csr_zero(int* __restrict__ cnt) {
    int i = blockIdx.x * 256 + threadIdx.x;
    if (i < NTYP * NPAD) cnt[i] = 0;
}
__global__ void k_csr_count(const int* __restrict__ eidx, int* __restrict__ cnt) {
    int i = blockIdx.x * 256 + threadIdx.x;
    if (i >= NTYP * N_EDGE) return;
    int t = i / N_EDGE, e = i - t * N_EDGE;
    int dst = eidx[(size_t)(t * 2 + 1) * N_EDGE + e];
    atomicAdd(&cnt[t * NPAD + dst], 1);
}
__global__ __launch_bounds__(1024) void k_csr_scan1(const int* __restrict__ cnt,
                                                    int* __restrict__ rowStart,
                                                    int* __restrict__ blockSum) {
    __shared__ int tmp[1024];
    int t = blockIdx.y, blk = blockIdx.x, tid = threadIdx.x;
    int idx = t * NPAD + blk * 1024 + tid;
    int v = cnt[idx];
    tmp[tid] = v;
    __syncthreads();
    for (int off = 1; off < 1024; off <<= 1) {
        int x = (tid >= off) ? tmp[tid - off] : 0;
        __syncthreads();
        tmp[tid] += x;
        __syncthreads();
    }
    rowStart[idx] = tmp[tid] - v;
    if (tid == 1023) blockSum[t * 64 + blk] = tmp[tid];
}
__global__ void k_csr_scan2(int* __restrict__ blockSum) {
    int t = threadIdx.x;
    if (t >= NTYP) return;
    int run = 0;
    for (int b = 0; b < BPT; ++b) {
        int v = blockSum[t * 64 + b];
        blockSum[t * 64 + b] = run;
        run += v;
    }
}
__global__ void k_csr_scan3(int* __restrict__ rowStart, const int* __restrict__ blockSum,
                            int* __restrict__ cursor) {
    int i = blockIdx.x * 256 + threadIdx.x;
    if (i >= NTYP * NPAD) return;
    int t = i / NPAD, n = i - t * NPAD;
    int v = rowStart[i] + blockSum[t * 64 + (n >> 10)];
    rowStart[i] = v;
    cursor[i] = v;
}
__global__ void k_csr_scatter(const int* __restrict__ eidx, int* __restrict__ cursor,
                              u16* __restrict__ sSrc, int* __restrict__ sEid) {
    int i = blockIdx.x * 256 + threadIdx.x;
    if (i >= NTYP * N_EDGE) return;
    int t = i / N_EDGE, e = i - t * N_EDGE;
    int src = eidx[(size_t)(t * 2) * N_EDGE + e];
    int dst = eidx[(size_t)(t * 2 + 1) * N_EDGE + e];
    int pos = atomicAdd(&cursor[t * NPAD + dst], 1);
    sSrc[(size_t)t * N_EDGE + pos] = (u16)src;
    sEid[(size_t)t * N_EDGE + pos] = e;
}

// ---------------------------------------------------------------------------
// Edge MLP for one type t
// ---------------------------------------------------------------------------
__global__ __launch_bounds__(256) void k_edge_mlp(
    const u16* __restrict__ Anodes, const int* __restrict__ eidx,
    const float* __restrict__ eattr, const float* __restrict__ W1,
    const float* __restrict__ b1, const float* __restrict__ W2,
    const float* __restrict__ b2, u16* __restrict__ outEa, int t)
{
    __shared__ float w1c[EDI][EH];
    __shared__ float w2s[EH][EH];
    __shared__ float b1s[EH], b2s[EH];
    int tid = threadIdx.x;
    for (int i = tid; i < EDI * EH; i += 256) w1c[i / EH][i % EH] = W1[(640 + i / EH) * EH + (i % EH)];
    for (int i = tid; i < EH * EH; i += 256) w2s[i / EH][i % EH] = W2[i];
    if (tid < EH) { b1s[tid] = b1[tid]; b2s[tid] = b2[tid]; }
    __syncthreads();

    int e = blockIdx.x * 256 + tid;
    if (e >= N_EDGE) return;
    int src = eidx[(size_t)(t * 2) * N_EDGE + e];
    int dst = eidx[(size_t)(t * 2 + 1) * N_EDGE + e];
    const float* eat = eattr + ((size_t)t * N_EDGE + e) * EDI;
    const u16* a1 = Anodes + (size_t)src * 64;
    const u16* a2 = Anodes + (size_t)dst * 64 + 32;

    float h1[EH];
#pragma unroll
    for (int j = 0; j < EH; ++j) h1[j] = b2f(a1[j]) + b2f(a2[j]) + b1s[j];
    for (int i = 0; i < EDI; ++i) {
        float v = eat[i];
#pragma unroll
        for (int j = 0; j < EH; ++j) h1[j] += v * w1c[i][j];
    }
#pragma unroll
    for (int j = 0; j < EH; ++j) h1[j] = h1[j] > 0.f ? h1[j] : 0.01f * h1[j];

    u16* orow = outEa + (size_t)e * EH;
    for (int j = 0; j < EH; ++j) {
        float o = b2s[j];
#pragma unroll
        for (int i = 0; i < EH; ++i) o += h1[i] * w2s[i][j];
        orow[j] = f2b(o);
    }
}

// ---------------------------------------------------------------------------
// Attention: one wave per dst node, CSR range, online softmax, unroll x2.
// Epilogue: acc[n] += av/l ; writes s row (32 vals + flag) into kq-major sST.
// ---------------------------------------------------------------------------
__global__ __launch_bounds__(256) void k_attn(
    const u16* __restrict__ qkv, const int* __restrict__ rowStart,
    const u16* __restrict__ sSrc, const int* __restrict__ sEid,
    const u16* __restrict__ ea, float* __restrict__ acc,
    u16* __restrict__ sST, int t34)
{
    int wave = threadIdx.x >> 6, lane = threadIdx.x & 63;
    int n = blockIdx.x * 4 + wave;
    if (n >= N_NODES) return;
    int eb = rowStart[n], ee = rowStart[n + 1];
    if (eb == ee) return;  // empty: acc untouched, s row stays zero

    const u16* qrow = qkv + (size_t)n * QLD;
    float q[5];
#pragma unroll
    for (int c = 0; c < 5; ++c) q[c] = b2f(qrow[c * 64 + lane]);
    float qwl = (lane < 33) ? b2f(qrow[960 + lane]) : 0.f;
    float qwbe = __shfl(qwl, 32, 64);
    float qw = (lane < 32) ? qwl : 0.f;
    const float RS = 0.05590169943749474f;  // 1/sqrt(320)

    float m = -INFINITY, l = 0.f, as = 0.f;
    float av[5] = {0.f, 0.f, 0.f, 0.f, 0.f};

    int ei = eb;
    for (; ei + 2 <= ee; ei += 2) {
        int s0 = sSrc[ei], s1 = sSrc[ei + 1];
        int id0 = sEid[ei], id1 = sEid[ei + 1];
        const u16* k0 = qkv + (size_t)s0 * QLD + 320;
        const u16* k1 = qkv + (size_t)s1 * QLD + 320;
        float ea0 = (lane < 32) ? b2f(ea[(size_t)id0 * 32 + lane]) : 0.f;
        float ea1 = (lane < 32) ? b2f(ea[(size_t)id1 * 32 + lane]) : 0.f;
        float d0 = qw * ea0, d1 = qw * ea1;
#pragma unroll
        for (int c = 0; c < 5; ++c) {
            d0 += q[c] * b2f(k0[c * 64 + lane]);
            d1 += q[c] * b2f(k1[c * 64 + lane]);
        }
#pragma unroll
        for (int off = 32; off > 0; off >>= 1) {
            d0 += __shfl_xor(d0, off, 64);
            d1 += __shfl_xor(d1, off, 64);
        }
        float a0 = (d0 + qwbe) * RS, a1 = (d1 + qwbe) * RS;
        float mn = fmaxf(m, fmaxf(a0, a1));
        float sc = __expf(m - mn);
        float p0 = __expf(a0 - mn), p1 = __expf(a1 - mn);
        l = l * sc + p0 + p1;
        const u16* v0 = k0 + 320;
        const u16* v1 = k1 + 320;
#pragma unroll
        for (int c = 0; c < 5; ++c)
            av[c] = av[c] * sc + p0 * b2f(v0[c * 64 + lane]) + p1 * b2f(v1[c * 64 + lane]);
        as = as * sc + p0 * ea0 + p1 * ea1;
        m = mn;
    }
    if (ei < ee) {
        int s0 = sSrc[ei];
        int id0 = sEid[ei];
        const u16* k0 = qkv + (size_t)s0 * QLD + 320;
        float ea0 = (lane < 32) ? b2f(ea[(size_t)id0 * 32 + lane]) : 0.f;
        float d0 = qw * ea0;
#pragma unroll
        for (int c = 0; c < 5; ++c) d0 += q[c] * b2f(k0[c * 64 + lane]);
#pragma unroll
        for (int off = 32; off > 0; off >>= 1) d0 += __shfl_xor(d0, off, 64);
        float a0 = (d0 + qwbe) * RS;
        float mn = fmaxf(m, a0);
        float sc = __expf(m - mn), p0 = __expf(a0 - mn);
        l = l * sc + p0;
        const u16* v0 = k0 + 320;
#pragma unroll
        for (int c = 0; c < 5; ++c) av[c] = av[c] * sc + p0 * b2f(v0[c * 64 + lane]);
        as = as * sc + p0 * ea0;
    }

    float inv = 1.f / l;
    float* arow = acc + (size_t)n * DIM;
#pragma unroll
    for (int c = 0; c < 5; ++c) arow[c * 64 + lane] += av[c] * inv;
    if (lane < 33) {
        int k = t34 + lane;
        float sv = (lane < 32) ? as * inv : 1.f;  // flag multiplies be row
        sST[((size_t)(k >> 3) * N_NODES + n) * 8 + (k & 7)] = f2b(sv);
    }
}

// ---------------------------------------------------------------------------
// Post: x_ = lrelu(acc/9); graph layernorm; h = 0.5*(h + x_) (h kq-major bf16)
// ---------------------------------------------------------------------------
__device__ __forceinline__ int lowerb(const int* a, int n, int v) {
    int lo = 0, hi = n;
    while (lo < hi) { int mid = (lo + hi) >> 1; if (a[mid] < v) lo = mid + 1; else hi = mid; }
    return lo;
}

__global__ __launch_bounds__(1024) void k_post(
    const float* __restrict__ acc, u16* __restrict__ hb,
    const int* __restrict__ batch, const float* __restrict__ gamma,
    const float* __restrict__ beta)
{
    int g = blockIdx.x;
    int start = lowerb(batch, N_NODES, g);
    int end   = lowerb(batch, N_NODES, g + 1);
    int cnt = end - start;
    if (cnt == 0) return;
    int i0 = start * DIM, i1 = end * DIM;

    float s = 0.f, ss = 0.f;
    for (int i = i0 + threadIdx.x; i < i1; i += 1024) {
        float v = acc[i] * (1.f / 9.f);
        v = v > 0.f ? v : 0.01f * v;
        s += v; ss += v * v;
    }
    __shared__ float rs[16], rss[16];
#pragma unroll
    for (int off = 32; off > 0; off >>= 1) { s += __shfl_xor(s, off, 64); ss += __shfl_xor(ss, off, 64); }
    int wave = threadIdx.x >> 6, lane = threadIdx.x & 63;
    if (lane == 0) { rs[wave] = s; rss[wave] = ss; }
    __syncthreads();
    if (threadIdx.x == 0) {
        float S = 0.f, SS = 0.f;
        for (int w = 0; w < 16; ++w) { S += rs[w]; SS += rss[w]; }
        float norm = (float)cnt * DIM;
        float mean = S / norm;
        float var = SS / norm - mean * mean;
        rs[0] = mean;
        rss[0] = rsqrtf(var + 1e-5f);
    }
    __syncthreads();
    float mean = rs[0], rsig = rss[0];
    for (int i = i0 + threadIdx.x; i < i1; i += 1024) {
        float v = acc[i] * (1.f / 9.f);
        v = v > 0.f ? v : 0.01f * v;
        int node = i / DIM, c = i - node * DIM;
        float o = (v - mean) * rsig * gamma[c] + beta[c];
        size_t hidx = ((size_t)(c >> 3) * N_NODES + node) * 8 + (c & 7);
        hb[hidx] = f2b(0.5f * (b2f(hb[hidx]) + o));
    }
}

__global__ __launch_bounds__(320) void k_maxpool(
    const u16* __restrict__ hb, const int* __restrict__ batch, float* __restrict__ out)
{
    int g = blockIdx.x, c = threadIdx.x;
    int start = lowerb(batch, N_NODES, g);
    int end   = lowerb(batch, N_NODES, g + 1);
    size_t base = (size_t)(c >> 3) * N_NODES * 8 + (c & 7);
    float m = -INFINITY;
    for (int n = start; n < end; ++n) m = fmaxf(m, b2f(hb[base + (size_t)n * 8]));
    out[(size_t)g * DIM + c] = m;
}

// ---------------------------------------------------------------------------
extern "C" void kernel_launch(void* const* d_in, const int* in_sizes, int n_in,
                              void* d_out, int out_size, void* d_ws, size_t ws_size,
                              hipStream_t stream)
{
    (void)in_sizes; (void)n_in; (void)out_size;
    const float* x     = (const float*)d_in[0];
    const int*   batch = (const int*)d_in[1];
    const int*   eidx  = (const int*)d_in[2];
    const float* eattr = (const float*)d_in[3];
    const float* W1 = (const float*)d_in[4];
    const float* b1 = (const float*)d_in[5];
    const float* W2 = (const float*)d_in[6];
    const float* b2 = (const float*)d_in[7];
    const float* Wq = (const float*)d_in[8];
    const float* bq = (const float*)d_in[9];
    const float* Wk = (const float*)d_in[10];
    const float* bk = (const float*)d_in[11];
    const float* Wv = (const float*)d_in[12];
    const float* bv = (const float*)d_in[13];
    const float* We = (const float*)d_in[14];
    const float* be = (const float*)d_in[15];
    const float* Ws = (const float*)d_in[16];
    const float* bs = (const float*)d_in[17];
    const float* gamma = (const float*)d_in[18];
    const float* beta  = (const float*)d_in[19];
    float* out = (float*)d_out;

    char* base = (char*)d_ws;
    size_t off = 0;
    auto carve = [&](size_t bytes) -> char* {
        char* r = base + off;
        off += (bytes + 255) & ~(size_t)255;
        return r;
    };
    u16*   hbKq    = (u16*)  carve((size_t)40 * N_NODES * 8 * 2 + 1024);  // 32 MB
    float* acc     = (float*)carve((size_t)N_NODES * DIM * 4);            // 64 MB
    u16*   qkv     = (u16*)  carve((size_t)N_NODES * QLD * 2);            // 100 MB
    u16*   sST     = (u16*)  carve((size_t)40 * N_NODES * 8 * 2 + 1024);  // 32 MB
    u16*   Anodes  = (u16*)  carve((size_t)N_NODES * 64 * 2);             // 6.4 MB
    u16*   BstQkv  = (u16*)  carve((size_t)27 * 40 * 1024 * 8 * 2);       // 17.7 MB
    float* biasQkv = (float*)carve((size_t)27 * 1024 * 4);
    u16*   BstSkip = (u16*)  carve((size_t)3 * 40 * 384 * 8 * 2);
    float* biasSkip= (float*)carve((size_t)3 * 384 * 4);
    u16*   BstSWe  = (u16*)  carve((size_t)3 * 40 * 384 * 8 * 2);
    u16*   BstW1   = (u16*)  carve((size_t)40 * 128 * 8 * 2);
    int*   cnt     = (int*)  carve((size_t)NTYP * NPAD * 4);
    int*   rowStart= (int*)  carve((size_t)NTYP * NPAD * 4);
    int*   blockSum= (int*)  carve((size_t)NTYP * 64 * 4);
    u16*   sSrc    = (u16*)  carve((size_t)NTYP * N_EDGE * 2);
    int*   sEid    = (int*)  carve((size_t)NTYP * N_EDGE * 4);
    size_t fixed = off;
    size_t bigBytes   = (size_t)NTYP * N_EDGE * EH * 2;
    size_t smallBytes = (size_t)N_EDGE * EH * 2;
    int bigEa = (ws_size >= fixed + bigBytes + (1u << 20)) ? 1 : 0;
    u16* newEa = (u16*)carve(bigEa ? bigBytes : smallBytes);

    // prep
    k_convert_x<<<(N_NODES * DIM + 255) / 256, 256, 0, stream>>>(x, hbKq);
    k_prep_qkvW<<<(27 * 40 * 1024 + 255) / 256, 256, 0, stream>>>(Wq, Wk, Wv, BstQkv);
    k_prep_ext<<<dim3(27, 11), 256, 0, stream>>>(Wq, bq, We, be, BstQkv, biasQkv);
    k_prep_qkvB<<<(27 * 1024 + 255) / 256, 256, 0, stream>>>(bq, bk, bv, biasQkv);
    k_prep_skipW<<<(3 * 320 * 384 + 255) / 256, 256, 0, stream>>>(Ws, BstSkip);
    k_prep_skipB<<<(3 * 384 + 255) / 256, 256, 0, stream>>>(bs, biasSkip);
    k_prep_sWe<<<(3 * 40 * 384 + 255) / 256, 256, 0, stream>>>(We, be, BstSWe);
    k_prep_w1W<<<(320 * 128 + 255) / 256, 256, 0, stream>>>(W1, BstW1);

    // CSR
    k_csr_zero<<<(NTYP * NPAD + 255) / 256, 256, 0, stream>>>(cnt);
    k_csr_count<<<(NTYP * N_EDGE + 255) / 256, 256, 0, stream>>>(eidx, cnt);
    k_csr_scan1<<<dim3(BPT, NTYP), 1024, 0, stream>>>(cnt, rowStart, blockSum);
    k_csr_scan2<<<1, 64, 0, stream>>>(blockSum);
    k_csr_scan3<<<(NTYP * NPAD + 255) / 256, 256, 0, stream>>>(rowStart, blockSum, cnt);
    k_csr_scatter<<<(NTYP * N_EDGE + 255) / 256, 256, 0, stream>>>(eidx, cnt, sSrc, sEid);

    const int mt = (N_NODES + 127) / 128;  // 391
    const int et = (N_EDGE + 255) / 256;
    // Anodes = x @ [W1a|W1b]
    gemm_kernel<<<dim3(1, mt), 256, 0, stream>>>(hbKq, N_NODES, BstW1, nullptr,
                                                 Anodes, nullptr, 64, 64, N_NODES, 128, 40, 0);
    if (bigEa) {
        for (int t = 0; t < NTYP; ++t)
            k_edge_mlp<<<dim3(et), 256, 0, stream>>>(
                Anodes, eidx, eattr, W1, b1, W2, b2, newEa + (size_t)t * N_EDGE * EH, t);
    }

    for (int b = 0; b < NBLK; ++b) {
        // acc = h @ sum_t(Ws) + sum_t(bs)
        gemm_kernel<<<dim3(3, mt), 256, 0, stream>>>(
            hbKq, N_NODES, BstSkip + (size_t)b * 40 * 384 * 8, biasSkip + b * 384,
            nullptr, acc, DIM, DIM, N_NODES, 384, 40, 1);
        hipMemsetAsync(sST, 0, (size_t)40 * N_NODES * 8 * 2, stream);
        for (int t = 0; t < NTYP; ++t) {
            int bt = b * NTYP + t;
            u16* eaT = bigEa ? (newEa + (size_t)t * N_EDGE * EH) : newEa;
            if (!bigEa)
                k_edge_mlp<<<dim3(et), 256, 0, stream>>>(
                    Anodes, eidx, eattr, W1, b1, W2, b2, eaT, t);
            gemm_kernel<<<dim3(8, mt), 256, 0, stream>>>(
                hbKq, N_NODES, BstQkv + (size_t)bt * 40 * 1024 * 8, biasQkv + bt * 1024,
                qkv, nullptr, QLD, 993, N_NODES, 1024, 40, 0);
            k_attn<<<dim3((N_NODES + 3) / 4), 256, 0, stream>>>(
                qkv, rowStart + t * NPAD, sSrc + (size_t)t * N_EDGE, sEid + (size_t)t * N_EDGE,
                eaT, acc, sST, t * 34);
        }
        // acc += s_all @ [We;be]_all   (batched over 9 types, K=306 padded 320)
        gemm_kernel<<<dim3(3, mt), 256, 0, stream>>>(
            sST, N_NODES, BstSWe + (size_t)b * 40 * 384 * 8, nullptr,
            nullptr, acc, DIM, DIM, N_NODES, 384, 40, 2);
        k_post<<<N_GRAPH, 1024, 0, stream>>>(acc, hbKq, batch,
                                             gamma + b * DIM, beta + b * DIM);
    }
    k_maxpool<<<N_GRAPH, 320, 0, stream>>>(hbKq, batch, out);
}